// Round 1
// baseline (194.965 us; speedup 1.0000x reference)
//
#include <hip/hip_runtime.h>

// Problem constants (B=4, S=2048, H=1024, E=8)
#define H 1024
#define E 8
#define T 8192          // B*S
#define CAP 1024        // T/E, capacity_factor=1.0 top-1

typedef __bf16 bf16x8 __attribute__((ext_vector_type(8)));
typedef float  f32x4  __attribute__((ext_vector_type(4)));

// round-to-nearest-even f32 -> bf16 bits (no NaN handling needed; inputs finite)
__device__ __forceinline__ unsigned short f2bf(float f) {
    union { float f; unsigned u; } v; v.f = f;
    unsigned r = v.u + 0x7FFFu + ((v.u >> 16) & 1u);
    return (unsigned short)(r >> 16);
}

// ---------------------------------------------------------------------------
// Kernel 1: gating. One wave per token: fp32 logits (tree-reduced), softmax,
// argmax (first-max tie-break = np.argmax), gate prob.
// ---------------------------------------------------------------------------
__global__ __launch_bounds__(256) void gate_kernel(
    const float* __restrict__ x, const float* __restrict__ wg,
    int* __restrict__ eid, float* __restrict__ gate) {
    const int wave = (blockIdx.x * blockDim.x + threadIdx.x) >> 6;
    const int lane = threadIdx.x & 63;
    const float* xr = x + (size_t)wave * H;
    float acc[E];
    #pragma unroll
    for (int e = 0; e < E; ++e) acc[e] = 0.f;
    #pragma unroll
    for (int q = 0; q < H / 64; ++q) {
        const int h = q * 64 + lane;
        const float xv = xr[h];
        const float* wr = wg + h * E;
        #pragma unroll
        for (int e = 0; e < E; ++e) acc[e] += xv * wr[e];
    }
    // 64-lane butterfly reduction for all 8 logits
    #pragma unroll
    for (int off = 32; off >= 1; off >>= 1) {
        #pragma unroll
        for (int e = 0; e < E; ++e) acc[e] += __shfl_xor(acc[e], off);
    }
    if (lane == 0) {
        float m = acc[0]; int best = 0;
        #pragma unroll
        for (int e = 1; e < E; ++e) if (acc[e] > m) { m = acc[e]; best = e; }
        float s = 0.f;
        #pragma unroll
        for (int e = 0; e < E; ++e) s += expf(acc[e] - m);
        eid[wave]  = best;
        gate[wave] = 1.0f / s;   // softmax prob of the argmax expert
    }
}

// ---------------------------------------------------------------------------
// Kernel 2: sequential capacity scan (single block, 256 threads, 32 tok/thr).
// Builds perm[e*CAP + slot] = token (or -1), zeroes gate for dropped tokens.
// ---------------------------------------------------------------------------
#define TPT 32
__global__ __launch_bounds__(256) void scan_kernel(
    const int* __restrict__ eid, float* __restrict__ gate,
    int* __restrict__ perm) {
    __shared__ int cnt[256][E];
    __shared__ int base[256][E];
    const int tid = threadIdx.x;

    for (int i = tid; i < E * CAP; i += 256) perm[i] = -1;

    const int t0 = tid * TPT;
    int le[TPT];
    int local[E];
    #pragma unroll
    for (int e = 0; e < E; ++e) local[e] = 0;
    for (int i = 0; i < TPT; ++i) { int e = eid[t0 + i]; le[i] = e; local[e]++; }
    #pragma unroll
    for (int e = 0; e < E; ++e) cnt[tid][e] = local[e];
    __syncthreads();
    if (tid < E) {            // serial exclusive scan per expert (8 threads)
        int run = 0;
        for (int i = 0; i < 256; ++i) { base[i][tid] = run; run += cnt[i][tid]; }
    }
    __syncthreads();
    #pragma unroll
    for (int e = 0; e < E; ++e) local[e] = base[tid][e];
    for (int i = 0; i < TPT; ++i) {
        const int e = le[i];
        const int pos = local[e]++;
        const int t = t0 + i;
        if (pos < CAP) perm[e * CAP + pos] = t;
        else gate[t] = 0.f;   // dropped; kept tokens have gate >= 1/8 > 0
    }
}

// ---------------------------------------------------------------------------
// Kernel 3: gathered per-expert GEMM + gated scatter epilogue.
// Block tile 128(slots) x 128(features), BK=32, 4 waves (2x2 of 64x64),
// mfma_f32_16x16x32_bf16, fp32->bf16 inline convert into padded LDS.
// Grid: (fb=8, mb=8, e=8).
// ---------------------------------------------------------------------------
#define BK  32
#define LDA 40   // BK + 8 pad (80 B row stride: 16B-aligned, 2-way banks = free)

__global__ __launch_bounds__(256) void moe_gemm(
    const float* __restrict__ x, const float* __restrict__ W,
    const float* __restrict__ bias, const int* __restrict__ perm,
    const float* __restrict__ gate, float* __restrict__ out) {
    __shared__ __align__(16) unsigned short As[128 * LDA];
    __shared__ __align__(16) unsigned short Bs[128 * LDA];
    __shared__ int   perm_s[128];
    __shared__ float gate_s[128];

    const int e   = blockIdx.z;
    const int mb  = blockIdx.y;
    const int fb  = blockIdx.x;
    const int tid = threadIdx.x;

    if (tid < 128) {
        const int t = perm[e * CAP + mb * 128 + tid];
        perm_s[tid] = t;
        gate_s[tid] = (t >= 0) ? gate[t] : 0.f;
    }
    __syncthreads();

    const int lane = tid & 63;
    const int wv = tid >> 6;
    const int wm = wv >> 1, wn = wv & 1;
    const int l16 = lane & 15, quad = lane >> 4;

    f32x4 acc[4][4] = {};

    const float* Wbase = W + (size_t)e * H * H + (size_t)(fb * 128) * H;

    for (int kt = 0; kt < H / BK; ++kt) {
        const int k0 = kt * BK;
        __syncthreads();   // previous iteration's frag reads done
        // stage A (gathered x rows) and B (W_e rows), fp32 -> bf16
        #pragma unroll
        for (int p = 0; p < 4; ++p) {
            const int c = p * 256 + tid;       // 1024 float4-chunks per tile
            const int row = c >> 3;
            const int col = (c & 7) * 4;
            const int t = perm_s[row];
            float4 va = (t >= 0) ? *(const float4*)(x + (size_t)t * H + k0 + col)
                                 : make_float4(0.f, 0.f, 0.f, 0.f);
            unsigned short* da = &As[row * LDA + col];
            da[0] = f2bf(va.x); da[1] = f2bf(va.y); da[2] = f2bf(va.z); da[3] = f2bf(va.w);
            float4 vb = *(const float4*)(Wbase + (size_t)row * H + k0 + col);
            unsigned short* db = &Bs[row * LDA + col];
            db[0] = f2bf(vb.x); db[1] = f2bf(vb.y); db[2] = f2bf(vb.z); db[3] = f2bf(vb.w);
        }
        __syncthreads();
        // fragments: A[m=lane&15][k=quad*8+j], B[n=lane&15][k=quad*8+j]
        bf16x8 af[4], bfr[4];
        #pragma unroll
        for (int i = 0; i < 4; ++i) {
            af[i]  = *(const bf16x8*)&As[(wm * 64 + i * 16 + l16) * LDA + quad * 8];
            bfr[i] = *(const bf16x8*)&Bs[(wn * 64 + i * 16 + l16) * LDA + quad * 8];
        }
        #pragma unroll
        for (int mi = 0; mi < 4; ++mi)
            #pragma unroll
            for (int ni = 0; ni < 4; ++ni)
                acc[mi][ni] = __builtin_amdgcn_mfma_f32_16x16x32_bf16(
                    af[mi], bfr[ni], acc[mi][ni], 0, 0, 0);
    }

    // epilogue: C/D layout col=lane&15, row=quad*4+reg (m89/m91-verified)
    float bv[4];
    #pragma unroll
    for (int ni = 0; ni < 4; ++ni)
        bv[ni] = bias[e * H + fb * 128 + wn * 64 + ni * 16 + l16];

    #pragma unroll
    for (int mi = 0; mi < 4; ++mi) {
        #pragma unroll
        for (int r = 0; r < 4; ++r) {
            const int rowl = wm * 64 + mi * 16 + quad * 4 + r;
            const int t = perm_s[rowl];
            if (t < 0) continue;
            const float g = gate_s[rowl];
            float* orow = out + (size_t)t * H + fb * 128 + wn * 64;
            #pragma unroll
            for (int ni = 0; ni < 4; ++ni)
                orow[ni * 16 + l16] = g * (acc[mi][ni][r] + bv[ni]);
        }
    }
}

// ---------------------------------------------------------------------------
// Kernel 4: zero output rows of dropped tokens (gate==0 sentinel).
// One wave per token; only dropped rows issue stores.
// ---------------------------------------------------------------------------
__global__ __launch_bounds__(256) void zero_dropped(
    const float* __restrict__ gate, float* __restrict__ out) {
    const int wave = (blockIdx.x * blockDim.x + threadIdx.x) >> 6;
    const int lane = threadIdx.x & 63;
    if (gate[wave] != 0.f) return;
    float4 z = make_float4(0.f, 0.f, 0.f, 0.f);
    float4* o = (float4*)(out + (size_t)wave * H);
    #pragma unroll
    for (int i = 0; i < H / 4 / 64; ++i) o[i * 64 + lane] = z;
}

extern "C" void kernel_launch(void* const* d_in, const int* in_sizes, int n_in,
                              void* d_out, int out_size, void* d_ws, size_t ws_size,
                              hipStream_t stream) {
    const float* x    = (const float*)d_in[0];  // [B,S,H] = [T,H]
    const float* wg   = (const float*)d_in[1];  // [H,E]
    const float* W    = (const float*)d_in[2];  // [E,H,H] (out,in)
    const float* bias = (const float*)d_in[3];  // [E,H]
    float* out = (float*)d_out;

    // workspace layout (96 KB): eid[T] | gate[T] | perm[E*CAP]
    int*   eid  = (int*)d_ws;
    float* gate = (float*)((char*)d_ws + (size_t)T * 4);
    int*   perm = (int*)((char*)d_ws + (size_t)T * 8);

    gate_kernel<<<T / 4, 256, 0, stream>>>(x, wg, eid, gate);
    scan_kernel<<<1, 256, 0, stream>>>(eid, gate, perm);
    moe_gemm<<<dim3(8, 8, 8), 256, 0, stream>>>(x, W, bias, perm, gate, out);
    zero_dropped<<<T / 4, 256, 0, stream>>>(gate, out);
}

// Round 2
// 176.764 us; speedup vs baseline: 1.1030x; 1.1030x over previous
//
#include <hip/hip_runtime.h>

// Problem constants (B=4, S=2048, H=1024, E=8)
#define H 1024
#define E 8
#define T 8192          // B*S
#define CAP 1024        // T/E, capacity_factor=1.0 top-1

typedef __bf16 bf16x8 __attribute__((ext_vector_type(8)));
typedef float  f32x4  __attribute__((ext_vector_type(4)));
typedef unsigned short u16;

// round-to-nearest-even f32 -> bf16 bits
__device__ __forceinline__ u16 f2bf(float f) {
    union { float f; unsigned u; } v; v.f = f;
    unsigned r = v.u + 0x7FFFu + ((v.u >> 16) & 1u);
    return (u16)(r >> 16);
}

// async global->LDS, 16 B per lane (global addr per-lane, LDS dest = base+lane*16)
typedef __attribute__((address_space(1))) const void* gas_t;
typedef __attribute__((address_space(3))) void* las_t;
__device__ __forceinline__ void gld16(const void* g, void* l) {
    __builtin_amdgcn_global_load_lds((gas_t)g, (las_t)l, 16, 0, 0);
}

// ---------------------------------------------------------------------------
// Kernel 1: gating (one wave per token) + fused x -> bf16 conversion.
// fp32 logits tree-reduced across the wave; argmax first-max = np.argmax.
// ---------------------------------------------------------------------------
__global__ __launch_bounds__(256) void gate_kernel(
    const float* __restrict__ x, const float* __restrict__ wg,
    int* __restrict__ eid, float* __restrict__ gate, u16* __restrict__ xbf) {
    const int wave = (blockIdx.x * blockDim.x + threadIdx.x) >> 6;
    const int lane = threadIdx.x & 63;
    const float* xr = x + (size_t)wave * H;
    float acc[E];
    #pragma unroll
    for (int e = 0; e < E; ++e) acc[e] = 0.f;
    #pragma unroll
    for (int q = 0; q < H / 64; ++q) {
        const int h = q * 64 + lane;
        const float xv = xr[h];
        if (xbf) xbf[(size_t)wave * H + h] = f2bf(xv);
        const float* wr = wg + h * E;
        #pragma unroll
        for (int e = 0; e < E; ++e) acc[e] += xv * wr[e];
    }
    #pragma unroll
    for (int off = 32; off >= 1; off >>= 1) {
        #pragma unroll
        for (int e = 0; e < E; ++e) acc[e] += __shfl_xor(acc[e], off);
    }
    if (lane == 0) {
        float m = acc[0]; int best = 0;
        #pragma unroll
        for (int e = 1; e < E; ++e) if (acc[e] > m) { m = acc[e]; best = e; }
        float s = 0.f;
        #pragma unroll
        for (int e = 0; e < E; ++e) s += expf(acc[e] - m);
        eid[wave]  = best;
        gate[wave] = 1.0f / s;
    }
}

// ---------------------------------------------------------------------------
// Kernel 2: W -> bf16 (grid-stride float4 -> 4x bf16)
// ---------------------------------------------------------------------------
__global__ __launch_bounds__(256) void cvt_kernel(
    const float* __restrict__ src, u16* __restrict__ dst, int n4) {
    int i = blockIdx.x * blockDim.x + threadIdx.x;
    const int stride = gridDim.x * blockDim.x;
    for (; i < n4; i += stride) {
        float4 v = ((const float4*)src)[i];
        ushort4 o;
        o.x = f2bf(v.x); o.y = f2bf(v.y); o.z = f2bf(v.z); o.w = f2bf(v.w);
        ((ushort4*)dst)[i] = o;
    }
}

// ---------------------------------------------------------------------------
// Kernel 3: capacity scan (single block). Register counters (no scratch
// spill from dynamic indexing), hierarchical LDS prefix.
// ---------------------------------------------------------------------------
#define TPT 32
__global__ __launch_bounds__(256) void scan_kernel(
    const int* __restrict__ eid, float* __restrict__ gate,
    int* __restrict__ perm) {
    __shared__ int cnt[256][E];
    __shared__ int base[256][E];
    __shared__ int part[E][8];
    const int tid = threadIdx.x;

    for (int i = tid; i < E * CAP; i += 256) perm[i] = -1;

    const int t0 = tid * TPT;
    int c[E];
    #pragma unroll
    for (int e = 0; e < E; ++e) c[e] = 0;
    for (int i = 0; i < TPT; ++i) {
        const int ei = eid[t0 + i];
        #pragma unroll
        for (int e = 0; e < E; ++e) c[e] += (ei == e);
    }
    #pragma unroll
    for (int e = 0; e < E; ++e) cnt[tid][e] = c[e];
    __syncthreads();
    if (tid < 64) {                       // partial sums: 8 experts x 8 segs of 32
        const int e = tid >> 3, j = tid & 7;
        int s = 0;
        for (int i = j * 32; i < j * 32 + 32; ++i) s += cnt[i][e];
        part[e][j] = s;
    }
    __syncthreads();
    if (tid < E) {                        // exclusive scan of 8 partials
        int run = 0;
        #pragma unroll
        for (int j = 0; j < 8; ++j) { int v = part[tid][j]; part[tid][j] = run; run += v; }
    }
    __syncthreads();
    if (tid < 64) {                       // replay to per-thread bases
        const int e = tid >> 3, j = tid & 7;
        int run = part[e][j];
        for (int i = j * 32; i < j * 32 + 32; ++i) { base[i][e] = run; run += cnt[i][e]; }
    }
    __syncthreads();
    #pragma unroll
    for (int e = 0; e < E; ++e) c[e] = base[tid][e];
    for (int i = 0; i < TPT; ++i) {
        const int t = t0 + i;
        const int ei = eid[t];
        int pos = 0;
        #pragma unroll
        for (int e = 0; e < E; ++e) if (ei == e) pos = c[e]++;
        if (pos < CAP) perm[ei * CAP + pos] = t;
        else gate[t] = 0.f;               // dropped; kept tokens have gate >= 1/8
    }
}

// ---------------------------------------------------------------------------
// Kernel 4 (fast path): bf16 gathered GEMM. Tile 128x128, BK=64, 4 waves
// (2x2 of 64x64), global_load_lds width-16 staging, XOR-swizzled LDS
// (16B chunk c of row r stored at slot c^(r&7); stride 128 B, no pad).
// Grid (fb=8, mb=8, e=8).
// ---------------------------------------------------------------------------
#define BK 64
__global__ __launch_bounds__(256) void moe_gemm_bf(
    const u16* __restrict__ xbf, const u16* __restrict__ Wbf,
    const float* __restrict__ bias, const int* __restrict__ perm,
    const float* __restrict__ gate, float* __restrict__ out) {
    __shared__ __align__(16) u16 As[128 * BK];   // 16 KB
    __shared__ __align__(16) u16 Bs[128 * BK];   // 16 KB
    __shared__ int   perm_s[128];
    __shared__ float gate_s[128];

    const int e   = blockIdx.z;
    const int mb  = blockIdx.y;
    const int fb  = blockIdx.x;
    const int tid = threadIdx.x;

    if (tid < 128) {
        const int t = perm[e * CAP + mb * 128 + tid];
        perm_s[tid] = t;
        gate_s[tid] = (t >= 0) ? gate[t] : 0.f;
    }
    __syncthreads();

    const int lane = tid & 63;
    const int wv = tid >> 6;
    const int wm = wv >> 1, wn = wv & 1;
    const int l16 = lane & 15, quad = lane >> 4;

    // --- staging setup: instr (wv,q) covers rows [(wv*4+q)*8, +8) ---
    const int rl   = lane >> 3;          // row within the 8-row group
    const int cch  = lane & 7;           // LDS 16B-chunk slot
    const int gch  = cch ^ rl;           // swizzled global chunk (r&7 == rl)
    const u16* ga[4]; const u16* gb[4];
    u16* la[4]; u16* lb[4];
    #pragma unroll
    for (int q = 0; q < 4; ++q) {
        const int r = (wv * 4 + q) * 8 + rl;
        const int tA = perm_s[r];
        const int tok = tA >= 0 ? tA : 0;         // safe row for empty slots
        ga[q] = xbf + (size_t)tok * H + gch * 8;
        gb[q] = Wbf + (size_t)e * H * H + (size_t)(fb * 128 + r) * H + gch * 8;
        la[q] = &As[(wv * 4 + q) * 512 + lane * 8];
        lb[q] = &Bs[(wv * 4 + q) * 512 + lane * 8];
    }

    f32x4 acc[4][4] = {};

    for (int kt = 0; kt < H / BK; ++kt) {
        __syncthreads();     // prior iteration's fragment reads complete
        #pragma unroll
        for (int q = 0; q < 4; ++q) {
            gld16(ga[q], la[q]);
            gld16(gb[q], lb[q]);
            ga[q] += BK; gb[q] += BK;
        }
        __syncthreads();     // staging (vmcnt) drained for all waves
        #pragma unroll
        for (int s = 0; s < 2; ++s) {
            bf16x8 af[4], bfr[4];
            const int cc = (s * 4 + quad) ^ (l16 & 7);  // de-swizzled chunk
            #pragma unroll
            for (int i = 0; i < 4; ++i) {
                af[i]  = *(const bf16x8*)&As[(wm * 64 + i * 16 + l16) * BK + cc * 8];
                bfr[i] = *(const bf16x8*)&Bs[(wn * 64 + i * 16 + l16) * BK + cc * 8];
            }
            #pragma unroll
            for (int mi = 0; mi < 4; ++mi)
                #pragma unroll
                for (int ni = 0; ni < 4; ++ni)
                    acc[mi][ni] = __builtin_amdgcn_mfma_f32_16x16x32_bf16(
                        af[mi], bfr[ni], acc[mi][ni], 0, 0, 0);
        }
    }

    // epilogue: C/D layout col=lane&15, row=quad*4+reg
    float bv[4];
    #pragma unroll
    for (int ni = 0; ni < 4; ++ni)
        bv[ni] = bias[e * H + fb * 128 + wn * 64 + ni * 16 + l16];

    #pragma unroll
    for (int mi = 0; mi < 4; ++mi) {
        #pragma unroll
        for (int r = 0; r < 4; ++r) {
            const int rowl = wm * 64 + mi * 16 + quad * 4 + r;
            const int t = perm_s[rowl];
            if (t < 0) continue;
            const float g = gate_s[rowl];
            float* orow = out + (size_t)t * H + fb * 128 + wn * 64;
            #pragma unroll
            for (int ni = 0; ni < 4; ++ni)
                orow[ni * 16 + l16] = g * (acc[mi][ni][r] + bv[ni]);
        }
    }
}

// ---------------------------------------------------------------------------
// Kernel 4 (fallback, ws too small): round-1 fp32-staging GEMM
// ---------------------------------------------------------------------------
#define LDA 40
__global__ __launch_bounds__(256) void moe_gemm_f32(
    const float* __restrict__ x, const float* __restrict__ W,
    const float* __restrict__ bias, const int* __restrict__ perm,
    const float* __restrict__ gate, float* __restrict__ out) {
    __shared__ __align__(16) u16 As[128 * LDA];
    __shared__ __align__(16) u16 Bs[128 * LDA];
    __shared__ int   perm_s[128];
    __shared__ float gate_s[128];

    const int e   = blockIdx.z;
    const int mb  = blockIdx.y;
    const int fb  = blockIdx.x;
    const int tid = threadIdx.x;

    if (tid < 128) {
        const int t = perm[e * CAP + mb * 128 + tid];
        perm_s[tid] = t;
        gate_s[tid] = (t >= 0) ? gate[t] : 0.f;
    }
    __syncthreads();

    const int lane = tid & 63;
    const int wv = tid >> 6;
    const int wm = wv >> 1, wn = wv & 1;
    const int l16 = lane & 15, quad = lane >> 4;

    f32x4 acc[4][4] = {};
    const float* Wbase = W + (size_t)e * H * H + (size_t)(fb * 128) * H;

    for (int kt = 0; kt < H / 32; ++kt) {
        const int k0 = kt * 32;
        __syncthreads();
        #pragma unroll
        for (int p = 0; p < 4; ++p) {
            const int cidx = p * 256 + tid;
            const int row = cidx >> 3;
            const int col = (cidx & 7) * 4;
            const int t = perm_s[row];
            float4 va = (t >= 0) ? *(const float4*)(x + (size_t)t * H + k0 + col)
                                 : make_float4(0.f, 0.f, 0.f, 0.f);
            u16* da = &As[row * LDA + col];
            da[0] = f2bf(va.x); da[1] = f2bf(va.y); da[2] = f2bf(va.z); da[3] = f2bf(va.w);
            float4 vb = *(const float4*)(Wbase + (size_t)row * H + k0 + col);
            u16* db = &Bs[row * LDA + col];
            db[0] = f2bf(vb.x); db[1] = f2bf(vb.y); db[2] = f2bf(vb.z); db[3] = f2bf(vb.w);
        }
        __syncthreads();
        bf16x8 af[4], bfr[4];
        #pragma unroll
        for (int i = 0; i < 4; ++i) {
            af[i]  = *(const bf16x8*)&As[(wm * 64 + i * 16 + l16) * LDA + quad * 8];
            bfr[i] = *(const bf16x8*)&Bs[(wn * 64 + i * 16 + l16) * LDA + quad * 8];
        }
        #pragma unroll
        for (int mi = 0; mi < 4; ++mi)
            #pragma unroll
            for (int ni = 0; ni < 4; ++ni)
                acc[mi][ni] = __builtin_amdgcn_mfma_f32_16x16x32_bf16(
                    af[mi], bfr[ni], acc[mi][ni], 0, 0, 0);
    }

    float bv[4];
    #pragma unroll
    for (int ni = 0; ni < 4; ++ni)
        bv[ni] = bias[e * H + fb * 128 + wn * 64 + ni * 16 + l16];
    #pragma unroll
    for (int mi = 0; mi < 4; ++mi) {
        #pragma unroll
        for (int r = 0; r < 4; ++r) {
            const int rowl = wm * 64 + mi * 16 + quad * 4 + r;
            const int t = perm_s[rowl];
            if (t < 0) continue;
            const float g = gate_s[rowl];
            float* orow = out + (size_t)t * H + fb * 128 + wn * 64;
            #pragma unroll
            for (int ni = 0; ni < 4; ++ni)
                orow[ni * 16 + l16] = g * (acc[mi][ni][r] + bv[ni]);
        }
    }
}

// ---------------------------------------------------------------------------
// Kernel 5: zero output rows of dropped tokens
// ---------------------------------------------------------------------------
__global__ __launch_bounds__(256) void zero_dropped(
    const float* __restrict__ gate, float* __restrict__ out) {
    const int wave = (blockIdx.x * blockDim.x + threadIdx.x) >> 6;
    const int lane = threadIdx.x & 63;
    if (gate[wave] != 0.f) return;
    float4 z = make_float4(0.f, 0.f, 0.f, 0.f);
    float4* o = (float4*)(out + (size_t)wave * H);
    #pragma unroll
    for (int i = 0; i < H / 4 / 64; ++i) o[i * 64 + lane] = z;
}

extern "C" void kernel_launch(void* const* d_in, const int* in_sizes, int n_in,
                              void* d_out, int out_size, void* d_ws, size_t ws_size,
                              hipStream_t stream) {
    const float* x    = (const float*)d_in[0];  // [T,H]
    const float* wg   = (const float*)d_in[1];  // [H,E]
    const float* W    = (const float*)d_in[2];  // [E,H,H]
    const float* bias = (const float*)d_in[3];  // [E,H]
    float* out = (float*)d_out;

    // ws: eid[T] | gate[T] | perm[E*CAP] | xbf[T*H] bf16 | Wbf[E*H*H] bf16
    int*   eid  = (int*)d_ws;
    float* gate = (float*)((char*)d_ws + (size_t)T * 4);
    int*   perm = (int*)((char*)d_ws + (size_t)T * 8);
    u16*   xbf  = (u16*)((char*)d_ws + (size_t)T * 12);
    u16*   Wbf  = xbf + (size_t)T * H;
    const size_t need = (size_t)T * 12 + (size_t)T * H * 2 + (size_t)E * H * H * 2;
    const bool fast = ws_size >= need;

    gate_kernel<<<T / 4, 256, 0, stream>>>(x, wg, eid, gate, fast ? xbf : nullptr);
    if (fast) cvt_kernel<<<2048, 256, 0, stream>>>(W, Wbf, E * H * H / 4);
    scan_kernel<<<1, 256, 0, stream>>>(eid, gate, perm);
    if (fast)
        moe_gemm_bf<<<dim3(8, 8, 8), 256, 0, stream>>>(xbf, Wbf, bias, perm, gate, out);
    else
        moe_gemm_f32<<<dim3(8, 8, 8), 256, 0, stream>>>(x, W, bias, perm, gate, out);
    zero_dropped<<<T / 4, 256, 0, stream>>>(gate, out);
}

// Round 3
// 156.510 us; speedup vs baseline: 1.2457x; 1.1294x over previous
//
#include <hip/hip_runtime.h>

// Problem constants (B=4, S=2048, H=1024, E=8)
#define H 1024
#define E 8
#define T 8192          // B*S
#define CAP 1024        // T/E, capacity_factor=1.0 top-1

typedef __bf16 bf16x8 __attribute__((ext_vector_type(8)));
typedef float  f32x4  __attribute__((ext_vector_type(4)));
typedef unsigned short u16;

// round-to-nearest-even f32 -> bf16 bits
__device__ __forceinline__ u16 f2bf(float f) {
    union { float f; unsigned u; } v; v.f = f;
    unsigned r = v.u + 0x7FFFu + ((v.u >> 16) & 1u);
    return (u16)(r >> 16);
}

// async global->LDS, 16 B per lane
typedef __attribute__((address_space(1))) const void* gas_t;
typedef __attribute__((address_space(3))) void* las_t;
__device__ __forceinline__ void gld16(const void* g, void* l) {
    __builtin_amdgcn_global_load_lds((gas_t)g, (las_t)l, 16, 0, 0);
}

// ---------------------------------------------------------------------------
// Kernel 1: fused gate + x->bf16 + W->bf16.
// Blocks [0,512): gating, 16 tokens/block (4 per wave). wg transposed+padded
// in LDS; float4 x loads; ushort4 xbf stores; 10-shuffle expert fold
// (expert ends at bit-reversed lane) + butterfly; first-max argmax = np.
// Blocks [512, 2048): grid-stride W fp32 -> bf16.
// ---------------------------------------------------------------------------
#define GATE_BLOCKS 512
#define CVT_BLOCKS  1536
#define WGP 1028     // padded row stride for wgs (floats)

__global__ __launch_bounds__(256) void gatecvt_kernel(
    const float* __restrict__ x, const float* __restrict__ wg,
    const float* __restrict__ W,
    int* __restrict__ eid, float* __restrict__ gate,
    u16* __restrict__ xbf, u16* __restrict__ Wbf) {
    __shared__ float wgs[E * WGP];   // ~33 KB
    const int tid = threadIdx.x;

    if (blockIdx.x >= GATE_BLOCKS) {       // ---- W conversion part ----
        int i = (blockIdx.x - GATE_BLOCKS) * 256 + tid;
        const int n4 = E * H * H / 4;
        const int stride = CVT_BLOCKS * 256;
        for (; i < n4; i += stride) {
            float4 v = ((const float4*)W)[i];
            ushort4 o;
            o.x = f2bf(v.x); o.y = f2bf(v.y); o.z = f2bf(v.z); o.w = f2bf(v.w);
            ((ushort4*)Wbf)[i] = o;
        }
        return;
    }

    // ---- gating part ----
    for (int i = tid; i < E * H; i += 256)           // wgs[e][h] = wg[h][e]
        wgs[(i & 7) * WGP + (i >> 3)] = wg[i];
    __syncthreads();

    const int wv = tid >> 6, lane = tid & 63;
    const int tbase = blockIdx.x * 16 + wv * 4;
    const int h00 = lane * 4;

    float a[4][8];
    #pragma unroll
    for (int j = 0; j < 4; ++j)
        #pragma unroll
        for (int e = 0; e < 8; ++e) a[j][e] = 0.f;

    #pragma unroll
    for (int q = 0; q < 4; ++q) {
        const int h0 = q * 256 + h00;
        float4 xv[4];
        #pragma unroll
        for (int j = 0; j < 4; ++j)
            xv[j] = *(const float4*)(x + (size_t)(tbase + j) * H + h0);
        #pragma unroll
        for (int j = 0; j < 4; ++j) {
            ushort4 o;
            o.x = f2bf(xv[j].x); o.y = f2bf(xv[j].y);
            o.z = f2bf(xv[j].z); o.w = f2bf(xv[j].w);
            *(ushort4*)(xbf + (size_t)(tbase + j) * H + h0) = o;
        }
        #pragma unroll
        for (int e = 0; e < 8; ++e) {
            const float4 w4 = *(const float4*)&wgs[e * WGP + h0];
            #pragma unroll
            for (int j = 0; j < 4; ++j)
                a[j][e] += xv[j].x * w4.x + xv[j].y * w4.y
                         + xv[j].z * w4.z + xv[j].w * w4.w;
        }
    }

    const bool b0 = lane & 1, b1 = lane & 2, b2 = lane & 4;
    // expert held by this lane after the fold = bit-reversed low-3 lane bits
    const int elane = ((lane & 1) << 2) | (lane & 2) | ((lane >> 2) & 1);

    #pragma unroll
    for (int j = 0; j < 4; ++j) {
        float* A = a[j];
        #pragma unroll
        for (int k = 0; k < 4; ++k) {     // fold 8 -> 4 (xor 1)
            float t = b0 ? A[k] : A[k + 4];
            t = __shfl_xor(t, 1);
            A[k] = (b0 ? A[k + 4] : A[k]) + t;
        }
        #pragma unroll
        for (int k = 0; k < 2; ++k) {     // fold 4 -> 2 (xor 2)
            float t = b1 ? A[k] : A[k + 2];
            t = __shfl_xor(t, 2);
            A[k] = (b1 ? A[k + 2] : A[k]) + t;
        }
        {                                  // fold 2 -> 1 (xor 4)
            float t = b2 ? A[0] : A[1];
            t = __shfl_xor(t, 4);
            A[0] = (b2 ? A[1] : A[0]) + t;
        }
        float v = A[0];
        v += __shfl_xor(v, 8); v += __shfl_xor(v, 16); v += __shfl_xor(v, 32);
        // every lane now holds logit[elane]; all-to-all over lane bits 0..2
        float m = v; int mi = elane;
        #pragma unroll
        for (int off = 1; off <= 4; off <<= 1) {
            float om = __shfl_xor(m, off);
            int   oi = __shfl_xor(mi, off);
            if (om > m || (om == m && oi < mi)) { m = om; mi = oi; }
        }
        float s = expf(v - m);
        s += __shfl_xor(s, 1); s += __shfl_xor(s, 2); s += __shfl_xor(s, 4);
        if (lane == 0) {
            eid[tbase + j]  = mi;
            gate[tbase + j] = 1.0f / s;   // softmax prob of argmax expert
        }
    }
}

// ---------------------------------------------------------------------------
// Kernel 2: capacity scan (single block), hierarchical LDS prefix.
// ---------------------------------------------------------------------------
#define TPT 32
__global__ __launch_bounds__(256) void scan_kernel(
    const int* __restrict__ eid, float* __restrict__ gate,
    int* __restrict__ perm) {
    __shared__ int cnt[256][E];
    __shared__ int base[256][E];
    __shared__ int part[E][8];
    const int tid = threadIdx.x;

    for (int i = tid; i < E * CAP; i += 256) perm[i] = -1;

    const int t0 = tid * TPT;
    int c[E];
    #pragma unroll
    for (int e = 0; e < E; ++e) c[e] = 0;
    for (int i = 0; i < TPT; ++i) {
        const int ei = eid[t0 + i];
        #pragma unroll
        for (int e = 0; e < E; ++e) c[e] += (ei == e);
    }
    #pragma unroll
    for (int e = 0; e < E; ++e) cnt[tid][e] = c[e];
    __syncthreads();
    if (tid < 64) {
        const int e = tid >> 3, j = tid & 7;
        int s = 0;
        for (int i = j * 32; i < j * 32 + 32; ++i) s += cnt[i][e];
        part[e][j] = s;
    }
    __syncthreads();
    if (tid < E) {
        int run = 0;
        #pragma unroll
        for (int j = 0; j < 8; ++j) { int v = part[tid][j]; part[tid][j] = run; run += v; }
    }
    __syncthreads();
    if (tid < 64) {
        const int e = tid >> 3, j = tid & 7;
        int run = part[e][j];
        for (int i = j * 32; i < j * 32 + 32; ++i) { base[i][e] = run; run += cnt[i][e]; }
    }
    __syncthreads();
    #pragma unroll
    for (int e = 0; e < E; ++e) c[e] = base[tid][e];
    for (int i = 0; i < TPT; ++i) {
        const int t = t0 + i;
        const int ei = eid[t];
        int pos = 0;
        #pragma unroll
        for (int e = 0; e < E; ++e) if (ei == e) pos = c[e]++;
        if (pos < CAP) perm[ei * CAP + pos] = t;
        else gate[t] = 0.f;               // dropped; kept tokens have gate >= 1/8
    }
}

// ---------------------------------------------------------------------------
// Kernel 3: bf16 gathered GEMM. Tile 128x128, BK=64, 4 waves (2x2 of 64x64),
// global_load_lds width-16 staging, XOR-swizzled LDS. Grid (fb=8, mb=8, e=8).
// ---------------------------------------------------------------------------
#define BK 64
__global__ __launch_bounds__(256) void moe_gemm_bf(
    const u16* __restrict__ xbf, const u16* __restrict__ Wbf,
    const float* __restrict__ bias, const int* __restrict__ perm,
    const float* __restrict__ gate, float* __restrict__ out) {
    __shared__ __align__(16) u16 As[128 * BK];   // 16 KB
    __shared__ __align__(16) u16 Bs[128 * BK];   // 16 KB
    __shared__ int   perm_s[128];
    __shared__ float gate_s[128];

    const int e   = blockIdx.z;
    const int mb  = blockIdx.y;
    const int fb  = blockIdx.x;
    const int tid = threadIdx.x;

    if (tid < 128) {
        const int t = perm[e * CAP + mb * 128 + tid];
        perm_s[tid] = t;
        gate_s[tid] = (t >= 0) ? gate[t] : 0.f;
    }
    __syncthreads();

    const int lane = tid & 63;
    const int wv = tid >> 6;
    const int wm = wv >> 1, wn = wv & 1;
    const int l16 = lane & 15, quad = lane >> 4;

    const int rl  = lane >> 3;           // row within the 8-row group
    const int cch = lane & 7;            // LDS 16B-chunk slot
    const int gch = cch ^ rl;            // swizzled global chunk
    const u16* ga[4]; const u16* gb[4];
    u16* la[4]; u16* lb[4];
    #pragma unroll
    for (int q = 0; q < 4; ++q) {
        const int r = (wv * 4 + q) * 8 + rl;
        const int tA = perm_s[r];
        const int tok = tA >= 0 ? tA : 0;
        ga[q] = xbf + (size_t)tok * H + gch * 8;
        gb[q] = Wbf + (size_t)e * H * H + (size_t)(fb * 128 + r) * H + gch * 8;
        la[q] = &As[(wv * 4 + q) * 512 + lane * 8];
        lb[q] = &Bs[(wv * 4 + q) * 512 + lane * 8];
    }

    f32x4 acc[4][4] = {};

    for (int kt = 0; kt < H / BK; ++kt) {
        __syncthreads();
        #pragma unroll
        for (int q = 0; q < 4; ++q) {
            gld16(ga[q], la[q]);
            gld16(gb[q], lb[q]);
            ga[q] += BK; gb[q] += BK;
        }
        __syncthreads();
        #pragma unroll
        for (int s = 0; s < 2; ++s) {
            bf16x8 af[4], bfr[4];
            const int cc = (s * 4 + quad) ^ (l16 & 7);
            #pragma unroll
            for (int i = 0; i < 4; ++i) {
                af[i]  = *(const bf16x8*)&As[(wm * 64 + i * 16 + l16) * BK + cc * 8];
                bfr[i] = *(const bf16x8*)&Bs[(wn * 64 + i * 16 + l16) * BK + cc * 8];
            }
            #pragma unroll
            for (int mi = 0; mi < 4; ++mi)
                #pragma unroll
                for (int ni = 0; ni < 4; ++ni)
                    acc[mi][ni] = __builtin_amdgcn_mfma_f32_16x16x32_bf16(
                        af[mi], bfr[ni], acc[mi][ni], 0, 0, 0);
        }
    }

    float bv[4];
    #pragma unroll
    for (int ni = 0; ni < 4; ++ni)
        bv[ni] = bias[e * H + fb * 128 + wn * 64 + ni * 16 + l16];

    #pragma unroll
    for (int mi = 0; mi < 4; ++mi) {
        #pragma unroll
        for (int r = 0; r < 4; ++r) {
            const int rowl = wm * 64 + mi * 16 + quad * 4 + r;
            const int t = perm_s[rowl];
            if (t < 0) continue;
            const float g = gate_s[rowl];
            float* orow = out + (size_t)t * H + fb * 128 + wn * 64;
            #pragma unroll
            for (int ni = 0; ni < 4; ++ni)
                orow[ni * 16 + l16] = g * (acc[mi][ni][r] + bv[ni]);
        }
    }
}

// ---------------------------------------------------------------------------
// Kernel 4: zero output rows of dropped tokens
// ---------------------------------------------------------------------------
__global__ __launch_bounds__(256) void zero_dropped(
    const float* __restrict__ gate, float* __restrict__ out) {
    const int wave = (blockIdx.x * blockDim.x + threadIdx.x) >> 6;
    const int lane = threadIdx.x & 63;
    if (gate[wave] != 0.f) return;
    float4 z = make_float4(0.f, 0.f, 0.f, 0.f);
    float4* o = (float4*)(out + (size_t)wave * H);
    #pragma unroll
    for (int i = 0; i < H / 4 / 64; ++i) o[i * 64 + lane] = z;
}

extern "C" void kernel_launch(void* const* d_in, const int* in_sizes, int n_in,
                              void* d_out, int out_size, void* d_ws, size_t ws_size,
                              hipStream_t stream) {
    const float* x    = (const float*)d_in[0];  // [T,H]
    const float* wg   = (const float*)d_in[1];  // [H,E]
    const float* W    = (const float*)d_in[2];  // [E,H,H]
    const float* bias = (const float*)d_in[3];  // [E,H]
    float* out = (float*)d_out;

    // ws: eid[T] | gate[T] | perm[E*CAP] | xbf[T*H] bf16 | Wbf[E*H*H] bf16
    int*   eid  = (int*)d_ws;
    float* gate = (float*)((char*)d_ws + (size_t)T * 4);
    int*   perm = (int*)((char*)d_ws + (size_t)T * 8);
    u16*   xbf  = (u16*)((char*)d_ws + (size_t)T * 12);
    u16*   Wbf  = xbf + (size_t)T * H;

    gatecvt_kernel<<<GATE_BLOCKS + CVT_BLOCKS, 256, 0, stream>>>(
        x, wg, W, eid, gate, xbf, Wbf);
    scan_kernel<<<1, 256, 0, stream>>>(eid, gate, perm);
    moe_gemm_bf<<<dim3(8, 8, 8), 256, 0, stream>>>(xbf, Wbf, bias, perm, gate, out);
    zero_dropped<<<T / 4, 256, 0, stream>>>(gate, out);
}